// Round 1
// baseline (120.624 us; speedup 1.0000x reference)
//
#include <hip/hip_runtime.h>
#include <hip/hip_bf16.h>

#define BB 8192
#define DD 256
#define ZN (2 * BB + 8)   // floats to zero: S_all, S_1, stats

typedef float f32x4 __attribute__((ext_vector_type(4)));
typedef __bf16 bf16x8 __attribute__((ext_vector_type(8)));

// sqrt(log2(e)/0.07): fn rows pre-scaled so MFMA acc = sim * log2(e)/T directly
#define FSCALE 4.53981600f

__device__ __forceinline__ void load16_to_lds(const void* g, void* l) {
    __builtin_amdgcn_global_load_lds(
        (const __attribute__((address_space(1))) unsigned int*)g,
        (__attribute__((address_space(3))) unsigned int*)l,
        16, 0, 0);
}

// ---------------------------------------------------------------------------
// prep: one wave per row. dist_sq vs center, sigma partials, writes the
// normalized+scaled row in MFMA FRAGMENT ORDER:
//   flat cell (16B) index = (g*8+kc)*64 + quad*16 + l15,  row = g*16+l15,
//   elems [kc*32+quad*8, +8). Also zeroes S_all/S_1/stats/out.
// ---------------------------------------------------------------------------
__global__ __launch_bounds__(256) void prep_kernel(
    const float* __restrict__ feat, const int* __restrict__ labels,
    const float* __restrict__ center, __hip_bfloat16* __restrict__ fnf,
    float* __restrict__ dist_sq, float* __restrict__ rowsum,
    float* __restrict__ rownsq, float* __restrict__ zacc,
    float* __restrict__ out)
{
    const int gid = blockIdx.x * 256 + threadIdx.x;
    if (gid < ZN) zacc[gid] = 0.0f;
    if (gid == 0) out[0] = 0.0f;

    const int wave = threadIdx.x >> 6;
    const int lane = threadIdx.x & 63;
    const int row  = blockIdx.x * 4 + wave;

    const float4* frow = reinterpret_cast<const float4*>(feat + (size_t)row * DD);
    const float4* crow = reinterpret_cast<const float4*>(center);
    float4 x = frow[lane];
    float4 c = crow[lane];

    float d0 = x.x - c.x, d1 = x.y - c.y, d2 = x.z - c.z, d3 = x.w - c.w;
    float dsq = d0*d0 + d1*d1 + d2*d2 + d3*d3;
    float nsq = x.x*x.x + x.y*x.y + x.z*x.z + x.w*x.w;
    float sx  = x.x + x.y + x.z + x.w;

    #pragma unroll
    for (int m = 1; m < 64; m <<= 1) {
        dsq += __shfl_xor(dsq, m);
        nsq += __shfl_xor(nsq, m);
        sx  += __shfl_xor(sx,  m);
    }

    float rn = FSCALE / fmaxf(sqrtf(nsq), 1e-12f);

    ushort4 u;
    u.x = __builtin_bit_cast(unsigned short, __float2bfloat16(x.x * rn));
    u.y = __builtin_bit_cast(unsigned short, __float2bfloat16(x.y * rn));
    u.z = __builtin_bit_cast(unsigned short, __float2bfloat16(x.z * rn));
    u.w = __builtin_bit_cast(unsigned short, __float2bfloat16(x.w * rn));

    // lane holds elems e=4*lane..+3: kc=lane/8, quad=(lane%8)/2, half=lane&1
    const int g    = row >> 4;
    const int l15r = row & 15;
    const int kc   = lane >> 3;
    const int qd   = (lane & 7) >> 1;
    const int half = lane & 1;
    const size_t cell = (size_t)((g * 8 + kc) * 64 + qd * 16 + l15r);
    reinterpret_cast<ushort4*>(fnf)[cell * 2 + half] = u;

    if (lane == 0) {
        const float m0 = (labels[row] == 0) ? 1.0f : 0.0f;
        dist_sq[row] = dsq;
        rowsum[row]  = sx  * m0;
        rownsq[row]  = nsq * m0;
    }
}

// ---------------------------------------------------------------------------
// reduce_stats: fold per-row partials into stats[0..2]. 96 atomics total.
// ---------------------------------------------------------------------------
__global__ __launch_bounds__(256) void reduce_stats_kernel(
    const int* __restrict__ labels, const float* __restrict__ rowsum,
    const float* __restrict__ rownsq, float* __restrict__ stats)
{
    __shared__ float sh[3][4];
    const int i = blockIdx.x * 256 + threadIdx.x;
    const int lane = threadIdx.x & 63;
    const int wave = threadIdx.x >> 6;

    float cnt = (labels[i] == 0) ? 1.0f : 0.0f;
    float sx  = rowsum[i];
    float nsq = rownsq[i];

    #pragma unroll
    for (int m = 1; m < 64; m <<= 1) {
        cnt += __shfl_xor(cnt, m);
        sx  += __shfl_xor(sx,  m);
        nsq += __shfl_xor(nsq, m);
    }
    if (lane == 0) { sh[0][wave] = cnt; sh[1][wave] = sx; sh[2][wave] = nsq; }
    __syncthreads();
    if (threadIdx.x == 0) {
        atomicAdd(&stats[0], sh[0][0] + sh[0][1] + sh[0][2] + sh[0][3]);
        atomicAdd(&stats[1], sh[1][0] + sh[1][1] + sh[1][2] + sh[1][3]);
        atomicAdd(&stats[2], sh[2][0] + sh[2][1] + sh[2][2] + sh[2][3]);
    }
}

// ---------------------------------------------------------------------------
// gram v2: fused Gram + masked exp row-sums.
// Changes vs v1:
//  * 64 rows/wave (a[4][8] = 128 VGPRs): halves LDS B-read traffic per output
//    (LDS was the heaviest pipe at ~20.5 us/CU). Block = 256 rows x 512 cols,
//    grid = 512 blocks = 2 blocks/CU, __launch_bounds__(256,2).
//  * Deferred epilogue (acc double-buffer accA/accB, unroll-by-2, static
//    names): tile t-1's exp2/sum VALU overlaps tile t's ds_read+MFMA instead
//    of serializing behind its own accumulator.
//  * Per-tile label weights staged once into LDS floats (wlab[512]) - removes
//    a global-load latency from every epilogue.
// ---------------------------------------------------------------------------
#define STAGE(T, BUF)                                                          \
  {                                                                            \
    const char* gsrc = (const char*)fnf +                                      \
        (size_t)((colstart + (T) * 16) >> 4) * 8192 + (size_t)tid * 16;        \
    load16_to_lds(gsrc,        &lds[BUF][wave * 1024]);                        \
    load16_to_lds(gsrc + 4096, &lds[BUF][4096 + wave * 1024]);                 \
  }

#define COMPUTE(ACC, BUF)                                                      \
  {                                                                            \
    const bf16x8* Bt = reinterpret_cast<const bf16x8*>(lds[BUF]);              \
    ACC[0] = (f32x4){0,0,0,0}; ACC[1] = (f32x4){0,0,0,0};                      \
    ACC[2] = (f32x4){0,0,0,0}; ACC[3] = (f32x4){0,0,0,0};                      \
    _Pragma("unroll")                                                          \
    for (int kc = 0; kc < 8; ++kc) {                                           \
      bf16x8 bv = Bt[kc * 64 + lane];                                          \
      ACC[0] = __builtin_amdgcn_mfma_f32_16x16x32_bf16(a[0][kc], bv, ACC[0], 0, 0, 0); \
      ACC[1] = __builtin_amdgcn_mfma_f32_16x16x32_bf16(a[1][kc], bv, ACC[1], 0, 0, 0); \
      ACC[2] = __builtin_amdgcn_mfma_f32_16x16x32_bf16(a[2][kc], bv, ACC[2], 0, 0, 0); \
      ACC[3] = __builtin_amdgcn_mfma_f32_16x16x32_bf16(a[3][kc], bv, ACC[3], 0, 0, 0); \
    }                                                                          \
  }

#define EPILOGUE(ACC, T)                                                       \
  {                                                                            \
    const int colbase = colstart + (T) * 16;                                   \
    const int bcol = colbase + l15;                                            \
    const float w1 = wlab[(T) * 16 + l15];                                     \
    if (colbase + 16 > rowbase && colbase < rowbase + 64) {                    \
      _Pragma("unroll")                                                        \
      for (int s = 0; s < 4; ++s) {                                            \
        _Pragma("unroll")                                                      \
        for (int r = 0; r < 4; ++r) {                                          \
          const int rr = rowbase + s * 16 + quad * 4 + r;                      \
          float e = (rr == bcol) ? 0.0f : exp2f(ACC[s][r]);                    \
          sall[s][r] += e; sp1[s][r] = fmaf(e, w1, sp1[s][r]);                 \
        }                                                                      \
      }                                                                        \
    } else {                                                                   \
      _Pragma("unroll")                                                        \
      for (int s = 0; s < 4; ++s) {                                            \
        _Pragma("unroll")                                                      \
        for (int r = 0; r < 4; ++r) {                                          \
          float e = exp2f(ACC[s][r]);                                          \
          sall[s][r] += e; sp1[s][r] = fmaf(e, w1, sp1[s][r]);                 \
        }                                                                      \
      }                                                                        \
    }                                                                          \
  }

__global__ __launch_bounds__(256, 2) void gram_kernel(
    const __hip_bfloat16* __restrict__ fnf, const int* __restrict__ labels,
    float* __restrict__ S_all, float* __restrict__ S_1)
{
    __shared__ __align__(16) char lds[2][8192];
    __shared__ float wlab[512];

    const int tid  = threadIdx.x;
    const int lane = tid & 63;
    const int wave = tid >> 6;
    const int l15  = lane & 15;
    const int quad = lane >> 4;

    const int cs = blockIdx.x & 15;       // col split  (16 splits x 512 cols)
    const int rb = blockIdx.x >> 4;       // row block  (32 blocks x 256 rows)
    const int rowbase  = rb * 256 + wave * 64;
    const int colstart = cs * 512;

    const bf16x8* __restrict__ F = reinterpret_cast<const bf16x8*>(fnf);

    // A fragments: 4 sub-tiles x 8 k-chunks = 64 rows/wave, coalesced loads
    bf16x8 a[4][8];
    #pragma unroll
    for (int s = 0; s < 4; ++s)
        #pragma unroll
        for (int kc = 0; kc < 8; ++kc)
            a[s][kc] = F[(size_t)((((rowbase >> 4) + s) * 8 + kc)) * 64 + lane];

    float sall[4][4], sp1[4][4];
    #pragma unroll
    for (int s = 0; s < 4; ++s)
        #pragma unroll
        for (int r = 0; r < 4; ++r) { sall[s][r] = 0.0f; sp1[s][r] = 0.0f; }

    STAGE(0, 0);
    #pragma unroll
    for (int i = tid; i < 512; i += 256) wlab[i] = (float)labels[colstart + i];

    f32x4 accA[4], accB[4];

    __syncthreads();          // stage(0) landed (vmcnt drained) + wlab visible
    STAGE(1, 1);
    COMPUTE(accA, 0);         // tile 0

    int t = 1;
    #pragma unroll 1
    for (int it = 0; it < 15; ++it) {
        // t odd: compute buf 1, prefetch even tile into buf 0
        __syncthreads();
        STAGE(t + 1, 0);
        COMPUTE(accB, 1);
        EPILOGUE(accA, t - 1);
        ++t;
        // t even: compute buf 0, prefetch odd tile into buf 1
        __syncthreads();
        STAGE(t + 1, 1);
        COMPUTE(accA, 0);
        EPILOGUE(accB, t - 1);
        ++t;
    }
    // t == 31
    __syncthreads();
    COMPUTE(accB, 1);
    EPILOGUE(accA, 30);
    EPILOGUE(accB, 31);

    // reduce over the 16 cols held across low lane bits, one atomic/row/block
    #pragma unroll
    for (int s = 0; s < 4; ++s)
        #pragma unroll
        for (int r = 0; r < 4; ++r) {
            float va = sall[s][r];
            float v1 = sp1[s][r];
            #pragma unroll
            for (int m = 1; m < 16; m <<= 1) {
                va += __shfl_xor(va, m);
                v1 += __shfl_xor(v1, m);
            }
            if (l15 == 0) {
                const int grow = rowbase + s * 16 + quad * 4 + r;
                atomicAdd(&S_all[grow], va);
                atomicAdd(&S_1[grow],  v1);
            }
        }
}

// ---------------------------------------------------------------------------
// finalize: per-row losses + mean reduction into out[0].
// ---------------------------------------------------------------------------
__global__ __launch_bounds__(256) void finalize_kernel(
    const int* __restrict__ labels, const float* __restrict__ dist_sq,
    const float* __restrict__ S_all, const float* __restrict__ S_1,
    const float* __restrict__ stats, const float* __restrict__ rsigma,
    float* __restrict__ out)
{
    const int i = blockIdx.x * 256 + threadIdx.x;

    const float n0   = stats[0];
    const float n_el = n0 * (float)DD;
    const float mean = stats[1] / n_el;
    const float var  = (stats[2] - n_el * mean * mean) / (n_el - 1.0f);
    const float sigma_new  = 0.9f * rsigma[0] + 0.1f * sqrtf(var);
    const float m_adaptive = 0.5f + 0.3f * sigma_new + 0.3f * (1.0f - 224.0f / 900.0f);

    const int l = labels[i];
    const float dsq = dist_sq[i];

    const float r_center = (l == 0) ? dsq : 0.0f;
    const float r_margin = (l == 1) ? fmaxf(m_adaptive - sqrtf(dsq), 0.0f) : 0.0f;

    const float sallv = S_all[i];
    const float s1v   = S_1[i];
    const float s0v   = sallv - s1v;
    const float pos = (l == 0) ? s0v : s1v;
    const float neg = (l == 0) ? s1v : s0v;

    const float n1 = (float)BB - n0;
    const float cnt_same = ((l == 0) ? n0 : n1) - 1.0f;
    const float cnt_diff = (l == 0) ? n1 : n0;

    float r_con = 0.0f;
    if (cnt_same > 0.0f && cnt_diff > 0.0f)
        r_con = logf(pos + neg + 1e-8f) - logf(pos);

    float tot = (r_center + r_margin + 0.5f * r_con) * (1.0f / (float)BB);

    #pragma unroll
    for (int m = 1; m < 64; m <<= 1) tot += __shfl_xor(tot, m);
    if ((threadIdx.x & 63) == 0) atomicAdd(out, tot);
}

// ---------------------------------------------------------------------------
// launch
// ---------------------------------------------------------------------------
extern "C" void kernel_launch(void* const* d_in, const int* in_sizes, int n_in,
                              void* d_out, int out_size, void* d_ws, size_t ws_size,
                              hipStream_t stream) {
    const float* feat   = (const float*)d_in[0];
    const int*   labels = (const int*)d_in[1];
    const float* center = (const float*)d_in[2];
    const float* rsigma = (const float*)d_in[3];
    float* out = (float*)d_out;

    char* ws = (char*)d_ws;
    __hip_bfloat16* fnf = (__hip_bfloat16*)ws;                    // B*D bf16 = 4 MB, fragment order
    float* dist_sq = (float*)(ws + (size_t)BB * DD * 2);          // B floats
    float* S_all   = dist_sq + BB;                                // B floats
    float* S_1     = S_all + BB;                                  // B floats
    float* stats   = S_1 + BB;                                    // 8 floats
    float* rowsum  = stats + 8;                                   // B floats
    float* rownsq  = rowsum + BB;                                 // B floats

    prep_kernel<<<dim3(BB / 4), dim3(256), 0, stream>>>(feat, labels, center, fnf,
                                                        dist_sq, rowsum, rownsq, S_all, out);
    reduce_stats_kernel<<<dim3(BB / 256), dim3(256), 0, stream>>>(labels, rowsum, rownsq, stats);
    gram_kernel<<<dim3(32 * 16), dim3(256), 0, stream>>>(fnf, labels, S_all, S_1);
    finalize_kernel<<<dim3(BB / 256), dim3(256), 0, stream>>>(labels, dist_sq, S_all, S_1, stats, rsigma, out);
}

// Round 2
// 108.375 us; speedup vs baseline: 1.1130x; 1.1130x over previous
//
#include <hip/hip_runtime.h>
#include <hip/hip_bf16.h>

#define BB 8192
#define DD 256
#define ZN (2 * BB)   // floats to zero: S_all, S_1

typedef float f32x4 __attribute__((ext_vector_type(4)));
typedef __bf16 bf16x8 __attribute__((ext_vector_type(8)));

// sqrt(log2(e)/0.07): fn rows pre-scaled so MFMA acc = sim * log2(e)/T directly
#define FSCALE 4.53981600f

__device__ __forceinline__ void load16_to_lds(const void* g, void* l) {
    __builtin_amdgcn_global_load_lds(
        (const __attribute__((address_space(1))) unsigned int*)g,
        (__attribute__((address_space(3))) unsigned int*)l,
        16, 0, 0);
}

// raw v_exp_f32: args here are |x| <= ~21, no range fixup needed
__device__ __forceinline__ float fast_exp2(float x) {
    float r;
    asm("v_exp_f32 %0, %1" : "=v"(r) : "v"(x));
    return r;
}

// ---------------------------------------------------------------------------
// prep: one wave per row. dist_sq vs center, sigma partials (block-reduced,
// race-free into stats_part[block]), writes the normalized+scaled row in MFMA
// FRAGMENT ORDER. Also zeroes S_all/S_1/out.
// ---------------------------------------------------------------------------
__global__ __launch_bounds__(256) void prep_kernel(
    const float* __restrict__ feat, const int* __restrict__ labels,
    const float* __restrict__ center, __hip_bfloat16* __restrict__ fnf,
    float* __restrict__ dist_sq, float* __restrict__ stats_part,
    float* __restrict__ zacc, float* __restrict__ out)
{
    __shared__ float sh[3][4];
    const int gid = blockIdx.x * 256 + threadIdx.x;
    if (gid < ZN) zacc[gid] = 0.0f;
    if (gid == 0) out[0] = 0.0f;

    const int wave = threadIdx.x >> 6;
    const int lane = threadIdx.x & 63;
    const int row  = blockIdx.x * 4 + wave;

    const float4* frow = reinterpret_cast<const float4*>(feat + (size_t)row * DD);
    const float4* crow = reinterpret_cast<const float4*>(center);
    float4 x = frow[lane];
    float4 c = crow[lane];

    float d0 = x.x - c.x, d1 = x.y - c.y, d2 = x.z - c.z, d3 = x.w - c.w;
    float dsq = d0*d0 + d1*d1 + d2*d2 + d3*d3;
    float nsq = x.x*x.x + x.y*x.y + x.z*x.z + x.w*x.w;
    float sx  = x.x + x.y + x.z + x.w;

    #pragma unroll
    for (int m = 1; m < 64; m <<= 1) {
        dsq += __shfl_xor(dsq, m);
        nsq += __shfl_xor(nsq, m);
        sx  += __shfl_xor(sx,  m);
    }

    float rn = FSCALE / fmaxf(sqrtf(nsq), 1e-12f);

    ushort4 u;
    u.x = __builtin_bit_cast(unsigned short, __float2bfloat16(x.x * rn));
    u.y = __builtin_bit_cast(unsigned short, __float2bfloat16(x.y * rn));
    u.z = __builtin_bit_cast(unsigned short, __float2bfloat16(x.z * rn));
    u.w = __builtin_bit_cast(unsigned short, __float2bfloat16(x.w * rn));

    // lane holds elems e=4*lane..+3: kc=lane/8, quad=(lane%8)/2, half=lane&1
    const int g    = row >> 4;
    const int l15r = row & 15;
    const int kc   = lane >> 3;
    const int qd   = (lane & 7) >> 1;
    const int half = lane & 1;
    const size_t cell = (size_t)((g * 8 + kc) * 64 + qd * 16 + l15r);
    reinterpret_cast<ushort4*>(fnf)[cell * 2 + half] = u;

    if (lane == 0) {
        const float m0 = (labels[row] == 0) ? 1.0f : 0.0f;
        dist_sq[row] = dsq;
        sh[0][wave] = m0;
        sh[1][wave] = sx  * m0;
        sh[2][wave] = nsq * m0;
    }
    __syncthreads();
    if (threadIdx.x == 0) {
        float* sp = stats_part + (size_t)blockIdx.x * 4;
        sp[0] = sh[0][0] + sh[0][1] + sh[0][2] + sh[0][3];
        sp[1] = sh[1][0] + sh[1][1] + sh[1][2] + sh[1][3];
        sp[2] = sh[2][0] + sh[2][1] + sh[2][2] + sh[2][3];
        sp[3] = 0.0f;
    }
}

// ---------------------------------------------------------------------------
// gram v3: fused Gram + masked exp row-sums.
// Changes vs v2 (which was NEUTRAL -> bottleneck was the per-tile vmcnt(0)
// drain at __syncthreads, not LDS/epilogue throughput):
//  * T3+T4: 4 LDS buffers, prefetch depth 3, raw s_barrier with counted
//    s_waitcnt vmcnt(4) (never 0 in steady state). Stage loads get ~3 phases
//    (>1500 cyc) to cover L2-miss/L3 latency instead of ~1 phase.
//  * T5: s_setprio(1) around the MFMA cluster.
//  * raw v_exp_f32 for exp2 (args bounded, skip libm fixup).
// Keeps: 64 rows/wave (a[4][8]), deferred epilogue, wlab in LDS.
// ---------------------------------------------------------------------------
#define STAGE(T, BUF)                                                          \
  {                                                                            \
    const char* gsrc = (const char*)fnf +                                      \
        (size_t)((colstart + (T) * 16) >> 4) * 8192 + (size_t)tid * 16;        \
    load16_to_lds(gsrc,        &lds[BUF][wave * 1024]);                        \
    load16_to_lds(gsrc + 4096, &lds[BUF][4096 + wave * 1024]);                 \
  }

// wait own stage(T) landed (NSTR stages still allowed in flight), all our
// ds_reads of the buffer about to be overwritten done, then barrier, then
// issue stage(T+3).
#define PHASE(T, NSTR)                                                         \
  {                                                                            \
    asm volatile("s_waitcnt vmcnt(" NSTR ") lgkmcnt(0)" ::: "memory");         \
    __builtin_amdgcn_sched_barrier(0);                                         \
    __builtin_amdgcn_s_barrier();                                              \
    if ((T) + 3 < 32) STAGE((T) + 3, ((T) + 3) & 3);                           \
  }

#define COMPUTE(ACC, BUF)                                                      \
  {                                                                            \
    const bf16x8* Bt = reinterpret_cast<const bf16x8*>(lds[BUF]);              \
    ACC[0] = (f32x4){0,0,0,0}; ACC[1] = (f32x4){0,0,0,0};                      \
    ACC[2] = (f32x4){0,0,0,0}; ACC[3] = (f32x4){0,0,0,0};                      \
    __builtin_amdgcn_s_setprio(1);                                             \
    _Pragma("unroll")                                                          \
    for (int kc = 0; kc < 8; ++kc) {                                           \
      bf16x8 bv = Bt[kc * 64 + lane];                                          \
      ACC[0] = __builtin_amdgcn_mfma_f32_16x16x32_bf16(a[0][kc], bv, ACC[0], 0, 0, 0); \
      ACC[1] = __builtin_amdgcn_mfma_f32_16x16x32_bf16(a[1][kc], bv, ACC[1], 0, 0, 0); \
      ACC[2] = __builtin_amdgcn_mfma_f32_16x16x32_bf16(a[2][kc], bv, ACC[2], 0, 0, 0); \
      ACC[3] = __builtin_amdgcn_mfma_f32_16x16x32_bf16(a[3][kc], bv, ACC[3], 0, 0, 0); \
    }                                                                          \
    __builtin_amdgcn_s_setprio(0);                                             \
  }

#define EPILOGUE(ACC, T)                                                       \
  {                                                                            \
    const int colbase = colstart + (T) * 16;                                   \
    const int bcol = colbase + l15;                                            \
    const float w1 = wlab[(T) * 16 + l15];                                     \
    if (colbase + 16 > rowbase && colbase < rowbase + 64) {                    \
      _Pragma("unroll")                                                        \
      for (int s = 0; s < 4; ++s) {                                            \
        _Pragma("unroll")                                                      \
        for (int r = 0; r < 4; ++r) {                                          \
          const int rr = rowbase + s * 16 + quad * 4 + r;                      \
          float e = (rr == bcol) ? 0.0f : fast_exp2(ACC[s][r]);                \
          sall[s][r] += e; sp1[s][r] = fmaf(e, w1, sp1[s][r]);                 \
        }                                                                      \
      }                                                                        \
    } else {                                                                   \
      _Pragma("unroll")                                                        \
      for (int s = 0; s < 4; ++s) {                                            \
        _Pragma("unroll")                                                      \
        for (int r = 0; r < 4; ++r) {                                          \
          float e = fast_exp2(ACC[s][r]);                                      \
          sall[s][r] += e; sp1[s][r] = fmaf(e, w1, sp1[s][r]);                 \
        }                                                                      \
      }                                                                        \
    }                                                                          \
  }

__global__ __launch_bounds__(256, 2) void gram_kernel(
    const __hip_bfloat16* __restrict__ fnf, const int* __restrict__ labels,
    float* __restrict__ S_all, float* __restrict__ S_1)
{
    __shared__ __align__(16) char lds[4][8192];
    __shared__ float wlab[512];

    const int tid  = threadIdx.x;
    const int lane = tid & 63;
    const int wave = tid >> 6;
    const int l15  = lane & 15;
    const int quad = lane >> 4;

    const int cs = blockIdx.x & 15;       // col split  (16 splits x 512 cols)
    const int rb = blockIdx.x >> 4;       // row block  (32 blocks x 256 rows)
    const int rowbase  = rb * 256 + wave * 64;
    const int colstart = cs * 512;

    const bf16x8* __restrict__ F = reinterpret_cast<const bf16x8*>(fnf);

    // A fragments: 4 sub-tiles x 8 k-chunks = 64 rows/wave, coalesced loads
    bf16x8 a[4][8];
    #pragma unroll
    for (int s = 0; s < 4; ++s)
        #pragma unroll
        for (int kc = 0; kc < 8; ++kc)
            a[s][kc] = F[(size_t)((((rowbase >> 4) + s) * 8 + kc)) * 64 + lane];

    float sall[4][4], sp1[4][4];
    #pragma unroll
    for (int s = 0; s < 4; ++s)
        #pragma unroll
        for (int r = 0; r < 4; ++r) { sall[s][r] = 0.0f; sp1[s][r] = 0.0f; }

    // prologue: 3 stages in flight, label weights to LDS
    STAGE(0, 0);
    STAGE(1, 1);
    STAGE(2, 2);
    #pragma unroll
    for (int i = tid; i < 512; i += 256) wlab[i] = (float)labels[colstart + i];

    f32x4 accA[4], accB[4];

    PHASE(0, "4"); COMPUTE(accA, 0);
    PHASE(1, "4"); COMPUTE(accB, 1); EPILOGUE(accA, 0);

    int t = 2;
    #pragma unroll 1
    for (int it = 0; it < 14; ++it) {
        PHASE(t, "4"); COMPUTE(accA, t & 3); EPILOGUE(accB, t - 1); ++t;
        PHASE(t, "4"); COMPUTE(accB, t & 3); EPILOGUE(accA, t - 1); ++t;
    }
    // t == 30, 31
    PHASE(30, "2"); COMPUTE(accA, 2); EPILOGUE(accB, 29);
    PHASE(31, "0"); COMPUTE(accB, 3); EPILOGUE(accA, 30);
    EPILOGUE(accB, 31);

    // reduce over the 16 cols held across low lane bits, one atomic/row/block
    #pragma unroll
    for (int s = 0; s < 4; ++s)
        #pragma unroll
        for (int r = 0; r < 4; ++r) {
            float va = sall[s][r];
            float v1 = sp1[s][r];
            #pragma unroll
            for (int m = 1; m < 16; m <<= 1) {
                va += __shfl_xor(va, m);
                v1 += __shfl_xor(v1, m);
            }
            if (l15 == 0) {
                const int grow = rowbase + s * 16 + quad * 4 + r;
                atomicAdd(&S_all[grow], va);
                atomicAdd(&S_1[grow],  v1);
            }
        }
}

// ---------------------------------------------------------------------------
// finalize: fold 2048 sigma partials (redundantly per block, coalesced
// float4), then per-row losses + mean reduction into out[0].
// ---------------------------------------------------------------------------
__global__ __launch_bounds__(256) void finalize_kernel(
    const int* __restrict__ labels, const float* __restrict__ dist_sq,
    const float* __restrict__ S_all, const float* __restrict__ S_1,
    const float* __restrict__ stats_part, const float* __restrict__ rsigma,
    float* __restrict__ out)
{
    __shared__ float sh[3][4];
    const int lane = threadIdx.x & 63;
    const int wave = threadIdx.x >> 6;

    float c = 0.0f, s = 0.0f, q = 0.0f;
    const float4* sp = reinterpret_cast<const float4*>(stats_part);
    #pragma unroll
    for (int b = 0; b < 8; ++b) {
        const float4 v = sp[b * 256 + threadIdx.x];
        c += v.x; s += v.y; q += v.z;
    }
    #pragma unroll
    for (int m = 1; m < 64; m <<= 1) {
        c += __shfl_xor(c, m);
        s += __shfl_xor(s, m);
        q += __shfl_xor(q, m);
    }
    if (lane == 0) { sh[0][wave] = c; sh[1][wave] = s; sh[2][wave] = q; }
    __syncthreads();

    const float n0   = sh[0][0] + sh[0][1] + sh[0][2] + sh[0][3];
    const float ssx  = sh[1][0] + sh[1][1] + sh[1][2] + sh[1][3];
    const float snsq = sh[2][0] + sh[2][1] + sh[2][2] + sh[2][3];

    const float n_el = n0 * (float)DD;
    const float mean = ssx / n_el;
    const float var  = (snsq - n_el * mean * mean) / (n_el - 1.0f);
    const float sigma_new  = 0.9f * rsigma[0] + 0.1f * sqrtf(var);
    const float m_adaptive = 0.5f + 0.3f * sigma_new + 0.3f * (1.0f - 224.0f / 900.0f);

    const int i = blockIdx.x * 256 + threadIdx.x;
    const int l = labels[i];
    const float dsq = dist_sq[i];

    const float r_center = (l == 0) ? dsq : 0.0f;
    const float r_margin = (l == 1) ? fmaxf(m_adaptive - sqrtf(dsq), 0.0f) : 0.0f;

    const float sallv = S_all[i];
    const float s1v   = S_1[i];
    const float s0v   = sallv - s1v;
    const float pos = (l == 0) ? s0v : s1v;
    const float neg = (l == 0) ? s1v : s0v;

    const float n1 = (float)BB - n0;
    const float cnt_same = ((l == 0) ? n0 : n1) - 1.0f;
    const float cnt_diff = (l == 0) ? n1 : n0;

    float r_con = 0.0f;
    if (cnt_same > 0.0f && cnt_diff > 0.0f)
        r_con = logf(pos + neg + 1e-8f) - logf(pos);

    float tot = (r_center + r_margin + 0.5f * r_con) * (1.0f / (float)BB);

    #pragma unroll
    for (int m = 1; m < 64; m <<= 1) tot += __shfl_xor(tot, m);
    if ((threadIdx.x & 63) == 0) atomicAdd(out, tot);
}

// ---------------------------------------------------------------------------
// launch
// ---------------------------------------------------------------------------
extern "C" void kernel_launch(void* const* d_in, const int* in_sizes, int n_in,
                              void* d_out, int out_size, void* d_ws, size_t ws_size,
                              hipStream_t stream) {
    const float* feat   = (const float*)d_in[0];
    const int*   labels = (const int*)d_in[1];
    const float* center = (const float*)d_in[2];
    const float* rsigma = (const float*)d_in[3];
    float* out = (float*)d_out;

    char* ws = (char*)d_ws;
    __hip_bfloat16* fnf = (__hip_bfloat16*)ws;                    // B*D bf16 = 4 MB, fragment order
    float* dist_sq   = (float*)(ws + (size_t)BB * DD * 2);        // B floats
    float* S_all     = dist_sq + BB;                              // B floats
    float* S_1       = S_all + BB;                                // B floats
    float* stats_part= S_1 + BB;                                  // 2048*4 floats

    prep_kernel<<<dim3(BB / 4), dim3(256), 0, stream>>>(feat, labels, center, fnf,
                                                        dist_sq, stats_part, S_all, out);
    gram_kernel<<<dim3(32 * 16), dim3(256), 0, stream>>>(fnf, labels, S_all, S_1);
    finalize_kernel<<<dim3(BB / 256), dim3(256), 0, stream>>>(labels, dist_sq, S_all, S_1,
                                                              stats_part, rsigma, out);
}